// Round 5
// baseline (1737.414 us; speedup 1.0000x reference)
//
#include <hip/hip_runtime.h>
#include <stdint.h>

#define N_ALL   16384
#define NPOINT  4096
#define KNN_K   32
#define BATCH   2
#define P_TOT   (BATCH*NPOINT*KNN_K)   /* 262144 */
#define EPSV    1e-5f
#define LEAK    0.1f

// ---- all scratch in module-static device memory; d_ws is NEVER touched ----
__device__ unsigned short g_knn[P_TOT];                                 // 512 KB
__device__ __attribute__((aligned(16))) float g_pt[BATCH*N_ALL*64];     // 8 MB
__device__ float g_W0f[64*68];
__device__ float g_W1f[64*64];
__device__ float g_W2f[128*64];
__device__ float g_part0[128], g_part1[128], g_part2[256];
__device__ float g_scsh0[128], g_scsh1[128], g_scsh2[256];

__device__ __forceinline__ unsigned long long shfl64(unsigned long long v, int src) {
  int lo = __shfl((int)(unsigned)(v & 0xFFFFFFFFULL), src, 64);
  int hi = __shfl((int)(unsigned)(v >> 32), src, 64);
  return (((unsigned long long)(unsigned)hi) << 32) | (unsigned)lo;
}
__device__ __forceinline__ unsigned long long shflup64(unsigned long long v) {
  int lo = __shfl_up((int)(unsigned)(v & 0xFFFFFFFFULL), 1, 64);
  int hi = __shfl_up((int)(unsigned)(v >> 32), 1, 64);
  return (((unsigned long long)(unsigned)hi) << 32) | (unsigned)lo;
}

// ---------------- new_xyz passthrough copy (2*3*4096 f32) ----------------
__global__ void k_newxyz(const float* __restrict__ xyz,
                         float* __restrict__ out) {
  int i = blockIdx.x * 256 + threadIdx.x;   // < 24576
  int s = i & 4095;
  int c = (i >> 12) % 3;
  int b = i / 12288;
  out[i] = xyz[(b * 3 + c) * N_ALL + s];
}

// ---------------- weight prep + zero stat accumulators ----------------
__global__ void k_wprep(const float* __restrict__ W0,
                        const float* __restrict__ W1,
                        const float* __restrict__ W2) {
  int t = threadIdx.x;
  for (int i = t; i < 64 * 68; i += 256) {
    int c = i / 68, j = i - c * 68;
    g_W0f[i] = (j < 67) ? W0[c * 67 + j] : 0.0f;
  }
  for (int i = t; i < 64 * 64; i += 256) g_W1f[i] = W1[i];
  for (int i = t; i < 128 * 64; i += 256) g_W2f[i] = W2[i];
  if (t < 128) { g_part0[t] = 0.f; g_part1[t] = 0.f; }
  g_part2[t] = 0.f;   // 256 floats
}

// ---------------- transpose points [b][c][n] -> g_pt [b][n][c] ----------------
__global__ __launch_bounds__(256) void k_tpose(const float* __restrict__ points) {
  __shared__ float tile[64][65];
  int b  = blockIdx.x >> 8;
  int n0 = (blockIdx.x & 255) << 6;
#pragma unroll
  for (int r = 0; r < 16; r++) {
    int lin = r * 256 + threadIdx.x;
    int c = lin >> 6, nn = lin & 63;
    tile[c][nn] = points[((size_t)(b * 64 + c)) * N_ALL + n0 + nn];
  }
  __syncthreads();
#pragma unroll
  for (int r = 0; r < 16; r++) {
    int lin = r * 256 + threadIdx.x;
    int nn = lin >> 6, c = lin & 63;
    g_pt[((size_t)(b * N_ALL + n0 + nn)) * 64 + c] = tile[c][nn];
  }
}

// ---------------- KNN: one wave/query; f32 distances in reference op order ----------------
__global__ __launch_bounds__(64) void k_knn(const float* __restrict__ xyz) {
#pragma clang fp contract(off)
  int b = blockIdx.x >> 12;
  int s = blockIdx.x & 4095;
  int lane = threadIdx.x;
  const float* xb = xyz + b * 3 * N_ALL;
  float qx = xb[s];
  float qy = xb[N_ALL + s];
  float qz = xb[2 * N_ALL + s];
  float qn = qx * qx + qy * qy + qz * qz;

  // lanes 0..31 hold sorted (keybits<<32|idx) ascending; lane31 = worst
  unsigned long long list = ~0ULL;
  for (int n0 = 0; n0 < N_ALL; n0 += 64) {
    int n = n0 + lane;
    float x = xb[n];
    float y = xb[N_ALL + n];
    float z = xb[2 * N_ALL + n];
    float xn = x * x + y * y + z * z;
    float dt = qx * x + qy * y + qz * z;
    float d = (qn + xn) - 2.0f * dt;
    unsigned du = __float_as_uint(d);
    du ^= ((unsigned)(((int)du) >> 31)) | 0x80000000u;   // order-preserving map
    unsigned long long cand = (((unsigned long long)du) << 32) | (unsigned)n;

    while (true) {
      unsigned long long worst = shfl64(list, 31);
      unsigned long long ball = __ballot(cand < worst);
      if (!ball) break;
      int j = __builtin_ctzll(ball);
      unsigned long long bk = shfl64(cand, j);
      if (lane == j) cand = ~0ULL;                 // retire
      unsigned long long up = shflup64(list);
      unsigned long long lm = __ballot(bk < list) & 0xFFFFFFFFULL;
      int pos = __builtin_ctzll(lm);               // bit31 guaranteed set
      if (lane == pos) list = bk;
      else if (lane > pos && lane < 32) list = up;
    }
  }
  if (lane < 32)
    g_knn[(blockIdx.x << 5) | lane] = (unsigned short)(list & 0xFFFF);
}

// ---------------- gather: direction(3) + grouped features(64), pad to 68 ----------------
__device__ __forceinline__ void gather_feat(const float* __restrict__ xyz,
                                            int p, float* feat) {
  int s = (p >> 5) & 4095;
  int b = p >> 17;
  int idx = g_knn[p];
  const float* xb = xyz + b * 3 * N_ALL;
  feat[0] = xb[idx] - xb[s];
  feat[1] = xb[N_ALL + idx] - xb[N_ALL + s];
  feat[2] = xb[2 * N_ALL + idx] - xb[2 * N_ALL + s];
  const float4* pr4 = (const float4*)(g_pt + ((size_t)(b * N_ALL + idx)) * 64);
#pragma unroll
  for (int i = 0; i < 16; i++) {
    float4 q = pr4[i];
    feat[3 + 4 * i + 0] = q.x;
    feat[3 + 4 * i + 1] = q.y;
    feat[3 + 4 * i + 2] = q.z;
    feat[3 + 4 * i + 3] = q.w;
  }
  feat[67] = 0.0f;
}

// ---------------- layer0 stats ----------------
__global__ __launch_bounds__(256) void k_l0stats(const float* __restrict__ xyz) {
  __shared__ float lsum[4][64], lsq[4][64];
  int p = blockIdx.x * 256 + threadIdx.x;
  float feat[68];
  gather_feat(xyz, p, feat);
  int wid = threadIdx.x >> 6, lane = threadIdx.x & 63;
  for (int c = 0; c < 64; c++) {
    float acc = 0.f;
#pragma unroll
    for (int j = 0; j < 68; j++) acc = fmaf(g_W0f[c * 68 + j], feat[j], acc);
    float v = acc, v2 = acc * acc;
#pragma unroll
    for (int off = 32; off; off >>= 1) { v += __shfl_xor(v, off, 64); v2 += __shfl_xor(v2, off, 64); }
    if (lane == 0) { lsum[wid][c] = v; lsq[wid][c] = v2; }
  }
  __syncthreads();
  if (threadIdx.x < 64) {
    int c = threadIdx.x;
    atomicAdd(g_part0 + c,      lsum[0][c] + lsum[1][c] + lsum[2][c] + lsum[3][c]);
    atomicAdd(g_part0 + 64 + c, lsq[0][c]  + lsq[1][c]  + lsq[2][c]  + lsq[3][c]);
  }
}

// ---------------- finalize BN stats -> scale/shift (globals, no symbol lookup) ----------------
__global__ void k_fin0(const float* __restrict__ g, const float* __restrict__ bta) {
  int c = threadIdx.x;   // 64
  float m = g_part0[c] / (float)P_TOT;
  float v = g_part0[64 + c] / (float)P_TOT - m * m;
  float sc = g[c] / sqrtf(v + EPSV);
  g_scsh0[c] = sc;
  g_scsh0[64 + c] = bta[c] - m * sc;
}
__global__ void k_fin1(const float* __restrict__ g, const float* __restrict__ bta) {
  int c = threadIdx.x;   // 64
  float m = g_part1[c] / (float)P_TOT;
  float v = g_part1[64 + c] / (float)P_TOT - m * m;
  float sc = g[c] / sqrtf(v + EPSV);
  g_scsh1[c] = sc;
  g_scsh1[64 + c] = bta[c] - m * sc;
}
__global__ void k_fin2(const float* __restrict__ g, const float* __restrict__ bta) {
  int c = threadIdx.x;   // 128
  float m = g_part2[c] / (float)P_TOT;
  float v = g_part2[128 + c] / (float)P_TOT - m * m;
  float sc = g[c] / sqrtf(v + EPSV);
  g_scsh2[c] = sc;
  g_scsh2[128 + c] = bta[c] - m * sc;
}

// ---------------- layer1 stats (recompute x0) ----------------
__global__ __launch_bounds__(256) void k_stats1(const float* __restrict__ xyz) {
  __shared__ float lsum[4][64], lsq[4][64];
  int p = blockIdx.x * 256 + threadIdx.x;
  float feat[68];
  gather_feat(xyz, p, feat);
  float act0[64];
  for (int c = 0; c < 64; c++) {
    float acc = 0.f;
#pragma unroll
    for (int j = 0; j < 68; j++) acc = fmaf(g_W0f[c * 68 + j], feat[j], acc);
    float a = acc * g_scsh0[c] + g_scsh0[64 + c];
    act0[c] = a >= 0.f ? a : LEAK * a;
  }
  int wid = threadIdx.x >> 6, lane = threadIdx.x & 63;
  for (int c = 0; c < 64; c++) {
    float acc = 0.f;
#pragma unroll
    for (int j = 0; j < 64; j++) acc = fmaf(g_W1f[c * 64 + j], act0[j], acc);
    float v = acc, v2 = acc * acc;
#pragma unroll
    for (int off = 32; off; off >>= 1) { v += __shfl_xor(v, off, 64); v2 += __shfl_xor(v2, off, 64); }
    if (lane == 0) { lsum[wid][c] = v; lsq[wid][c] = v2; }
  }
  __syncthreads();
  if (threadIdx.x < 64) {
    int c = threadIdx.x;
    atomicAdd(g_part1 + c,      lsum[0][c] + lsum[1][c] + lsum[2][c] + lsum[3][c]);
    atomicAdd(g_part1 + 64 + c, lsq[0][c]  + lsq[1][c]  + lsq[2][c]  + lsq[3][c]);
  }
}

// ---------------- layer2 stats (recompute x0,x1) ----------------
__global__ __launch_bounds__(256) void k_stats2(const float* __restrict__ xyz) {
  __shared__ float lsum[4][128], lsq[4][128];
  int p = blockIdx.x * 256 + threadIdx.x;
  float feat[68];
  gather_feat(xyz, p, feat);
  float act0[64];
  for (int c = 0; c < 64; c++) {
    float acc = 0.f;
#pragma unroll
    for (int j = 0; j < 68; j++) acc = fmaf(g_W0f[c * 68 + j], feat[j], acc);
    float a = acc * g_scsh0[c] + g_scsh0[64 + c];
    act0[c] = a >= 0.f ? a : LEAK * a;
  }
  float act1[64];
  for (int c = 0; c < 64; c++) {
    float acc = 0.f;
#pragma unroll
    for (int j = 0; j < 64; j++) acc = fmaf(g_W1f[c * 64 + j], act0[j], acc);
    float a = acc * g_scsh1[c] + g_scsh1[64 + c];
    act1[c] = a >= 0.f ? a : LEAK * a;
  }
  int wid = threadIdx.x >> 6, lane = threadIdx.x & 63;
  for (int c = 0; c < 128; c++) {
    float acc = 0.f;
#pragma unroll
    for (int j = 0; j < 64; j++) acc = fmaf(g_W2f[c * 64 + j], act1[j], acc);
    float v = acc, v2 = acc * acc;
#pragma unroll
    for (int off = 32; off; off >>= 1) { v += __shfl_xor(v, off, 64); v2 += __shfl_xor(v2, off, 64); }
    if (lane == 0) { lsum[wid][c] = v; lsq[wid][c] = v2; }
  }
  __syncthreads();
  if (threadIdx.x < 128) {
    int c = threadIdx.x;
    atomicAdd(g_part2 + c,       lsum[0][c] + lsum[1][c] + lsum[2][c] + lsum[3][c]);
    atomicAdd(g_part2 + 128 + c, lsq[0][c]  + lsq[1][c]  + lsq[2][c]  + lsq[3][c]);
  }
}

// ---------------- output: recompute all layers, BN+act, max over k, write f32 ----------------
__global__ __launch_bounds__(256) void k_out(const float* __restrict__ xyz,
                                             float* __restrict__ out) {
  int p = blockIdx.x * 256 + threadIdx.x;
  int k = p & 31;
  int s = (p >> 5) & 4095;
  int b = p >> 17;
  float feat[68];
  gather_feat(xyz, p, feat);
  float act0[64];
  for (int c = 0; c < 64; c++) {
    float acc = 0.f;
#pragma unroll
    for (int j = 0; j < 68; j++) acc = fmaf(g_W0f[c * 68 + j], feat[j], acc);
    float a = acc * g_scsh0[c] + g_scsh0[64 + c];
    act0[c] = a >= 0.f ? a : LEAK * a;
  }
  float act1[64];
  for (int c = 0; c < 64; c++) {
    float acc = 0.f;
#pragma unroll
    for (int j = 0; j < 64; j++) acc = fmaf(g_W1f[c * 64 + j], act0[j], acc);
    float a = acc * g_scsh1[c] + g_scsh1[64 + c];
    act1[c] = a >= 0.f ? a : LEAK * a;
  }
  for (int c = 0; c < 128; c++) {
    float acc = 0.f;
#pragma unroll
    for (int j = 0; j < 64; j++) acc = fmaf(g_W2f[c * 64 + j], act1[j], acc);
    float t = acc * g_scsh2[c] + g_scsh2[128 + c];
    t = t >= 0.f ? t : LEAK * t;
    float mx = t;
#pragma unroll
    for (int off = 16; off; off >>= 1)   // stays within 32-lane k-group
      mx = fmaxf(mx, __shfl_xor(mx, off, 64));
    if (k == 0)
      out[24576 + (((b * 128 + c) << 12) | s)] = mx;
  }
}

extern "C" void kernel_launch(void* const* d_in, const int* in_sizes, int n_in,
                              void* d_out, int out_size, void* d_ws, size_t ws_size,
                              hipStream_t stream) {
  (void)in_sizes; (void)n_in; (void)out_size; (void)d_ws; (void)ws_size;
  const float* xyz    = (const float*)d_in[0];
  const float* points = (const float*)d_in[1];
  const float* W0     = (const float*)d_in[2];
  const float* W1     = (const float*)d_in[3];
  const float* W2     = (const float*)d_in[4];
  const float* g0     = (const float*)d_in[5];
  const float* b0     = (const float*)d_in[6];
  const float* g1     = (const float*)d_in[7];
  const float* b1     = (const float*)d_in[8];
  const float* g2     = (const float*)d_in[9];
  const float* b2     = (const float*)d_in[10];
  float* out = (float*)d_out;

  hipLaunchKernelGGL(k_newxyz,  dim3(96),   dim3(256), 0, stream, xyz, out);
  hipLaunchKernelGGL(k_wprep,   dim3(1),    dim3(256), 0, stream, W0, W1, W2);
  hipLaunchKernelGGL(k_tpose,   dim3(512),  dim3(256), 0, stream, points);
  hipLaunchKernelGGL(k_knn,     dim3(8192), dim3(64),  0, stream, xyz);
  hipLaunchKernelGGL(k_l0stats, dim3(1024), dim3(256), 0, stream, xyz);
  hipLaunchKernelGGL(k_fin0,    dim3(1),    dim3(64),  0, stream, g0, b0);
  hipLaunchKernelGGL(k_stats1,  dim3(1024), dim3(256), 0, stream, xyz);
  hipLaunchKernelGGL(k_fin1,    dim3(1),    dim3(64),  0, stream, g1, b1);
  hipLaunchKernelGGL(k_stats2,  dim3(1024), dim3(256), 0, stream, xyz);
  hipLaunchKernelGGL(k_fin2,    dim3(1),    dim3(128), 0, stream, g2, b2);
  hipLaunchKernelGGL(k_out,     dim3(1024), dim3(256), 0, stream, xyz, out);
}

// Round 6
// 737.194 us; speedup vs baseline: 2.3568x; 2.3568x over previous
//
#include <hip/hip_runtime.h>
#include <stdint.h>

#define N_ALL   16384
#define NPOINT  4096
#define KNN_K   32
#define BATCH   2
#define P_TOT   (BATCH*NPOINT*KNN_K)   /* 262144 */
#define EPSV    1e-5f
#define LEAK    0.1f

// ---- all scratch in module-static device memory; d_ws is NEVER touched ----
__device__ unsigned short g_knn[P_TOT];                                 // 512 KB
__device__ __attribute__((aligned(16))) float g_pt[BATCH*N_ALL*64];     // 8 MB
__device__ __attribute__((aligned(16))) float g_x0[(size_t)64*P_TOT];   // 67 MB
__device__ __attribute__((aligned(16))) float g_x1[(size_t)64*P_TOT];   // 67 MB
__device__ float g_ymax[BATCH*128*NPOINT];                              // 4 MB
__device__ float g_ymin[BATCH*128*NPOINT];                              // 4 MB
__device__ float g_W0f[64*68];
__device__ float g_W1f[64*64];
__device__ float g_W2f[128*64];
__device__ float g_part0[128], g_part1[128], g_part2[256];
__device__ float g_scsh0[128], g_scsh1[128], g_scsh2[256];

__device__ __forceinline__ unsigned long long shfl64(unsigned long long v, int src) {
  int lo = __shfl((int)(unsigned)(v & 0xFFFFFFFFULL), src, 64);
  int hi = __shfl((int)(unsigned)(v >> 32), src, 64);
  return (((unsigned long long)(unsigned)hi) << 32) | (unsigned)lo;
}
__device__ __forceinline__ unsigned long long shflup64(unsigned long long v) {
  int lo = __shfl_up((int)(unsigned)(v & 0xFFFFFFFFULL), 1, 64);
  int hi = __shfl_up((int)(unsigned)(v >> 32), 1, 64);
  return (((unsigned long long)(unsigned)hi) << 32) | (unsigned)lo;
}

// ---------------- new_xyz passthrough copy (2*3*4096 f32) ----------------
__global__ void k_newxyz(const float* __restrict__ xyz,
                         float* __restrict__ out) {
  int i = blockIdx.x * 256 + threadIdx.x;   // < 24576
  int s = i & 4095;
  int c = (i >> 12) % 3;
  int b = i / 12288;
  out[i] = xyz[(b * 3 + c) * N_ALL + s];
}

// ---------------- weight prep + zero stat accumulators ----------------
__global__ void k_wprep(const float* __restrict__ W0,
                        const float* __restrict__ W1,
                        const float* __restrict__ W2) {
  int t = threadIdx.x;
  for (int i = t; i < 64 * 68; i += 256) {
    int c = i / 68, j = i - c * 68;
    g_W0f[i] = (j < 67) ? W0[c * 67 + j] : 0.0f;
  }
  for (int i = t; i < 64 * 64; i += 256) g_W1f[i] = W1[i];
  for (int i = t; i < 128 * 64; i += 256) g_W2f[i] = W2[i];
  if (t < 128) { g_part0[t] = 0.f; g_part1[t] = 0.f; }
  g_part2[t] = 0.f;   // 256 floats
}

// ---------------- transpose points [b][c][n] -> g_pt [b][n][c] ----------------
__global__ __launch_bounds__(256) void k_tpose(const float* __restrict__ points) {
  __shared__ float tile[64][65];
  int b  = blockIdx.x >> 8;
  int n0 = (blockIdx.x & 255) << 6;
#pragma unroll
  for (int r = 0; r < 16; r++) {
    int lin = r * 256 + threadIdx.x;
    int c = lin >> 6, nn = lin & 63;
    tile[c][nn] = points[((size_t)(b * 64 + c)) * N_ALL + n0 + nn];
  }
  __syncthreads();
#pragma unroll
  for (int r = 0; r < 16; r++) {
    int lin = r * 256 + threadIdx.x;
    int nn = lin >> 6, c = lin & 63;
    g_pt[((size_t)(b * N_ALL + n0 + nn)) * 64 + c] = tile[c][nn];
  }
}

// ---------------- KNN: one wave/query; f32 distances in reference op order ----------------
__global__ __launch_bounds__(64) void k_knn(const float* __restrict__ xyz) {
#pragma clang fp contract(off)
  int b = blockIdx.x >> 12;
  int s = blockIdx.x & 4095;
  int lane = threadIdx.x;
  const float* xb = xyz + b * 3 * N_ALL;
  float qx = xb[s];
  float qy = xb[N_ALL + s];
  float qz = xb[2 * N_ALL + s];
  float qn = qx * qx + qy * qy + qz * qz;

  unsigned long long list = ~0ULL;   // lanes 0..31: sorted (keybits<<32|idx)
  for (int n0 = 0; n0 < N_ALL; n0 += 64) {
    int n = n0 + lane;
    float x = xb[n];
    float y = xb[N_ALL + n];
    float z = xb[2 * N_ALL + n];
    float xn = x * x + y * y + z * z;
    float dt = qx * x + qy * y + qz * z;
    float d = (qn + xn) - 2.0f * dt;
    unsigned du = __float_as_uint(d);
    du ^= ((unsigned)(((int)du) >> 31)) | 0x80000000u;   // order-preserving
    unsigned long long cand = (((unsigned long long)du) << 32) | (unsigned)n;

    while (true) {
      unsigned long long worst = shfl64(list, 31);
      unsigned long long ball = __ballot(cand < worst);
      if (!ball) break;
      int j = __builtin_ctzll(ball);
      unsigned long long bk = shfl64(cand, j);
      if (lane == j) cand = ~0ULL;                 // retire
      unsigned long long up = shflup64(list);
      unsigned long long lm = __ballot(bk < list) & 0xFFFFFFFFULL;
      int pos = __builtin_ctzll(lm);               // bit31 guaranteed set
      if (lane == pos) list = bk;
      else if (lane > pos && lane < 32) list = up;
    }
  }
  if (lane < 32)
    g_knn[(blockIdx.x << 5) | lane] = (unsigned short)(list & 0xFFFF);
}

// ---------------- pass A: gather + layer0 -> g_x0, stats0 ----------------
__global__ __launch_bounds__(256, 4) void k_l0(const float* __restrict__ xyz) {
  __shared__ float lsum[4][64], lsq[4][64];
  int p = blockIdx.x * 256 + threadIdx.x;
  int s = (p >> 5) & 4095;
  int b = p >> 17;
  int idx = g_knn[p];
  const float* xb = xyz + b * 3 * N_ALL;
  float feat[68];
  feat[0] = xb[idx] - xb[s];
  feat[1] = xb[N_ALL + idx] - xb[N_ALL + s];
  feat[2] = xb[2 * N_ALL + idx] - xb[2 * N_ALL + s];
  const float4* pr4 = (const float4*)(g_pt + ((size_t)(b * N_ALL + idx)) * 64);
#pragma unroll
  for (int i = 0; i < 16; i++) {
    float4 q = pr4[i];
    feat[3 + 4 * i + 0] = q.x;
    feat[3 + 4 * i + 1] = q.y;
    feat[3 + 4 * i + 2] = q.z;
    feat[3 + 4 * i + 3] = q.w;
  }
  feat[67] = 0.0f;

  int wid = threadIdx.x >> 6, lane = threadIdx.x & 63;
  for (int c = 0; c < 64; c++) {
    float acc = 0.f;
#pragma unroll
    for (int j = 0; j < 68; j++) acc = fmaf(g_W0f[c * 68 + j], feat[j], acc);
    g_x0[(size_t)c * P_TOT + p] = acc;
    float v = acc, v2 = acc * acc;
#pragma unroll
    for (int off = 32; off; off >>= 1) { v += __shfl_xor(v, off, 64); v2 += __shfl_xor(v2, off, 64); }
    if (lane == 0) { lsum[wid][c] = v; lsq[wid][c] = v2; }
  }
  __syncthreads();
  if (threadIdx.x < 64) {
    int c = threadIdx.x;
    atomicAdd(g_part0 + c,      lsum[0][c] + lsum[1][c] + lsum[2][c] + lsum[3][c]);
    atomicAdd(g_part0 + 64 + c, lsq[0][c]  + lsq[1][c]  + lsq[2][c]  + lsq[3][c]);
  }
}

// ---------------- finalize BN stats -> scale/shift ----------------
__global__ void k_fin0(const float* __restrict__ g, const float* __restrict__ bta) {
  int c = threadIdx.x;   // 64
  float m = g_part0[c] / (float)P_TOT;
  float v = g_part0[64 + c] / (float)P_TOT - m * m;
  float sc = g[c] / sqrtf(v + EPSV);
  g_scsh0[c] = sc;
  g_scsh0[64 + c] = bta[c] - m * sc;
}
__global__ void k_fin1(const float* __restrict__ g, const float* __restrict__ bta) {
  int c = threadIdx.x;   // 64
  float m = g_part1[c] / (float)P_TOT;
  float v = g_part1[64 + c] / (float)P_TOT - m * m;
  float sc = g[c] / sqrtf(v + EPSV);
  g_scsh1[c] = sc;
  g_scsh1[64 + c] = bta[c] - m * sc;
}
__global__ void k_fin2(const float* __restrict__ g, const float* __restrict__ bta) {
  int c = threadIdx.x;   // 128
  float m = g_part2[c] / (float)P_TOT;
  float v = g_part2[128 + c] / (float)P_TOT - m * m;
  float sc = g[c] / sqrtf(v + EPSV);
  g_scsh2[c] = sc;
  g_scsh2[128 + c] = bta[c] - m * sc;
}

// ---------------- pass B: BN0+act on g_x0, layer1 -> g_x1, stats1 ----------------
__global__ __launch_bounds__(256, 4) void k_l1() {
  __shared__ float lsum[4][64], lsq[4][64];
  int p = blockIdx.x * 256 + threadIdx.x;
  float act0[64];
#pragma unroll
  for (int c = 0; c < 64; c++) {
    float a = g_x0[(size_t)c * P_TOT + p] * g_scsh0[c] + g_scsh0[64 + c];
    act0[c] = a >= 0.f ? a : LEAK * a;
  }
  int wid = threadIdx.x >> 6, lane = threadIdx.x & 63;
  for (int c = 0; c < 64; c++) {
    float acc = 0.f;
#pragma unroll
    for (int j = 0; j < 64; j++) acc = fmaf(g_W1f[c * 64 + j], act0[j], acc);
    g_x1[(size_t)c * P_TOT + p] = acc;
    float v = acc, v2 = acc * acc;
#pragma unroll
    for (int off = 32; off; off >>= 1) { v += __shfl_xor(v, off, 64); v2 += __shfl_xor(v2, off, 64); }
    if (lane == 0) { lsum[wid][c] = v; lsq[wid][c] = v2; }
  }
  __syncthreads();
  if (threadIdx.x < 64) {
    int c = threadIdx.x;
    atomicAdd(g_part1 + c,      lsum[0][c] + lsum[1][c] + lsum[2][c] + lsum[3][c]);
    atomicAdd(g_part1 + 64 + c, lsq[0][c]  + lsq[1][c]  + lsq[2][c]  + lsq[3][c]);
  }
}

// ---------------- pass C: BN1+act on g_x1, layer2, stats2 + k-extrema ----------------
__global__ __launch_bounds__(256, 4) void k_l2() {
  __shared__ float lsum[4][128], lsq[4][128];
  int p = blockIdx.x * 256 + threadIdx.x;
  int k = p & 31;
  int s = (p >> 5) & 4095;
  int b = p >> 17;
  float act1[64];
#pragma unroll
  for (int c = 0; c < 64; c++) {
    float a = g_x1[(size_t)c * P_TOT + p] * g_scsh1[c] + g_scsh1[64 + c];
    act1[c] = a >= 0.f ? a : LEAK * a;
  }
  int wid = threadIdx.x >> 6, lane = threadIdx.x & 63;
  for (int c = 0; c < 128; c++) {
    float acc = 0.f;
#pragma unroll
    for (int j = 0; j < 64; j++) acc = fmaf(g_W2f[c * 64 + j], act1[j], acc);
    float v = acc, v2 = acc * acc;
#pragma unroll
    for (int off = 32; off; off >>= 1) { v += __shfl_xor(v, off, 64); v2 += __shfl_xor(v2, off, 64); }
    if (lane == 0) { lsum[wid][c] = v; lsq[wid][c] = v2; }
    float mx = acc, mn = acc;
#pragma unroll
    for (int off = 16; off; off >>= 1) {   // within 32-lane k-group
      mx = fmaxf(mx, __shfl_xor(mx, off, 64));
      mn = fminf(mn, __shfl_xor(mn, off, 64));
    }
    if (k == 0) {
      int o = ((b * 128 + c) << 12) | s;
      g_ymax[o] = mx; g_ymin[o] = mn;
    }
  }
  __syncthreads();
  if (threadIdx.x < 128) {
    int c = threadIdx.x;
    atomicAdd(g_part2 + c,       lsum[0][c] + lsum[1][c] + lsum[2][c] + lsum[3][c]);
    atomicAdd(g_part2 + 128 + c, lsq[0][c]  + lsq[1][c]  + lsq[2][c]  + lsq[3][c]);
  }
}

// ---------------- epilogue: BN2+act over k-extremum, write f32 ----------------
__global__ void k_epi(float* __restrict__ out) {
  int i = blockIdx.x * 256 + threadIdx.x;   // < 1048576
  int c = (i >> 12) & 127;
  float sc = g_scsh2[c], sh = g_scsh2[128 + c];
  float v = (sc >= 0.f) ? g_ymax[i] : g_ymin[i];
  float t = v * sc + sh;
  t = (t >= 0.f) ? t : LEAK * t;
  out[24576 + i] = t;
}

extern "C" void kernel_launch(void* const* d_in, const int* in_sizes, int n_in,
                              void* d_out, int out_size, void* d_ws, size_t ws_size,
                              hipStream_t stream) {
  (void)in_sizes; (void)n_in; (void)out_size; (void)d_ws; (void)ws_size;
  const float* xyz    = (const float*)d_in[0];
  const float* points = (const float*)d_in[1];
  const float* W0     = (const float*)d_in[2];
  const float* W1     = (const float*)d_in[3];
  const float* W2     = (const float*)d_in[4];
  const float* g0     = (const float*)d_in[5];
  const float* b0     = (const float*)d_in[6];
  const float* g1     = (const float*)d_in[7];
  const float* b1     = (const float*)d_in[8];
  const float* g2     = (const float*)d_in[9];
  const float* b2     = (const float*)d_in[10];
  float* out = (float*)d_out;

  hipLaunchKernelGGL(k_newxyz,  dim3(96),   dim3(256), 0, stream, xyz, out);
  hipLaunchKernelGGL(k_wprep,   dim3(1),    dim3(256), 0, stream, W0, W1, W2);
  hipLaunchKernelGGL(k_tpose,   dim3(512),  dim3(256), 0, stream, points);
  hipLaunchKernelGGL(k_knn,     dim3(8192), dim3(64),  0, stream, xyz);
  hipLaunchKernelGGL(k_l0,      dim3(1024), dim3(256), 0, stream, xyz);
  hipLaunchKernelGGL(k_fin0,    dim3(1),    dim3(64),  0, stream, g0, b0);
  hipLaunchKernelGGL(k_l1,      dim3(1024), dim3(256), 0, stream);
  hipLaunchKernelGGL(k_fin1,    dim3(1),    dim3(64),  0, stream, g1, b1);
  hipLaunchKernelGGL(k_l2,      dim3(1024), dim3(256), 0, stream);
  hipLaunchKernelGGL(k_fin2,    dim3(1),    dim3(128), 0, stream, g2, b2);
  hipLaunchKernelGGL(k_epi,     dim3(4096), dim3(256), 0, stream, out);
}

// Round 7
// 673.310 us; speedup vs baseline: 2.5804x; 1.0949x over previous
//
#include <hip/hip_runtime.h>
#include <stdint.h>

#define N_ALL   16384
#define NPOINT  4096
#define KNN_K   32
#define BATCH   2
#define P_TOT   (BATCH*NPOINT*KNN_K)   /* 262144 */
#define EPSV    1e-5f
#define LEAK    0.1f

// ---- all scratch in module-static device memory; d_ws is NEVER touched ----
__device__ unsigned short g_knn[P_TOT];                                  // 512 KB
__device__ __attribute__((aligned(16))) float g_pt[BATCH*N_ALL*64];      // 8 MB
__device__ __attribute__((aligned(16))) float g_x0[(size_t)64*P_TOT];    // 67 MB
__device__ __attribute__((aligned(16))) float g_x1[(size_t)64*P_TOT];    // 67 MB
__device__ __attribute__((aligned(16))) float g_x2[(size_t)128*P_TOT];   // 134 MB
__device__ float g_W0f[64*68];
__device__ float g_W1f[64*64];
__device__ float g_W2f[128*64];
__device__ float g_part0[128], g_part1[128], g_part2[256];

__device__ __forceinline__ unsigned long long shfl64(unsigned long long v, int src) {
  int lo = __shfl((int)(unsigned)(v & 0xFFFFFFFFULL), src, 64);
  int hi = __shfl((int)(unsigned)(v >> 32), src, 64);
  return (((unsigned long long)(unsigned)hi) << 32) | (unsigned)lo;
}
__device__ __forceinline__ unsigned long long shflup64(unsigned long long v) {
  int lo = __shfl_up((int)(unsigned)(v & 0xFFFFFFFFULL), 1, 64);
  int hi = __shfl_up((int)(unsigned)(v >> 32), 1, 64);
  return (((unsigned long long)(unsigned)hi) << 32) | (unsigned)lo;
}
__device__ __forceinline__ unsigned long long umin64(unsigned long long a, unsigned long long b) {
  return a < b ? a : b;
}

// ---------------- new_xyz passthrough copy (2*3*4096 f32) ----------------
__global__ void k_newxyz(const float* __restrict__ xyz, float* __restrict__ out) {
  int i = blockIdx.x * 256 + threadIdx.x;   // < 24576
  int s = i & 4095;
  int c = (i >> 12) % 3;
  int b = i / 12288;
  out[i] = xyz[(b * 3 + c) * N_ALL + s];
}

// ---------------- weight prep + zero stat accumulators ----------------
__global__ void k_wprep(const float* __restrict__ W0, const float* __restrict__ W1,
                        const float* __restrict__ W2) {
  int t = threadIdx.x;
  for (int i = t; i < 64 * 68; i += 256) {
    int c = i / 68, j = i - c * 68;
    g_W0f[i] = (j < 67) ? W0[c * 67 + j] : 0.0f;
  }
  for (int i = t; i < 64 * 64; i += 256) g_W1f[i] = W1[i];
  for (int i = t; i < 128 * 64; i += 256) g_W2f[i] = W2[i];
  if (t < 128) { g_part0[t] = 0.f; g_part1[t] = 0.f; }
  g_part2[t] = 0.f;
}

// ---------------- transpose points [b][c][n] -> g_pt [b][n][c] ----------------
__global__ __launch_bounds__(256) void k_tpose(const float* __restrict__ points) {
  __shared__ float tile[64][65];
  int b  = blockIdx.x >> 8;
  int n0 = (blockIdx.x & 255) << 6;
#pragma unroll
  for (int r = 0; r < 16; r++) {
    int lin = r * 256 + threadIdx.x;
    int c = lin >> 6, nn = lin & 63;
    tile[c][nn] = points[((size_t)(b * 64 + c)) * N_ALL + n0 + nn];
  }
  __syncthreads();
#pragma unroll
  for (int r = 0; r < 16; r++) {
    int lin = r * 256 + threadIdx.x;
    int nn = lin >> 6, c = lin & 63;
    g_pt[((size_t)(b * N_ALL + n0 + nn)) * 64 + c] = tile[c][nn];
  }
}

// ---------------- KNN: one wave/query; cached-worst fast path, 4x unroll ----------------
__global__ __launch_bounds__(64) void k_knn(const float* __restrict__ xyz) {
#pragma clang fp contract(off)
  int b = blockIdx.x >> 12;
  int s = blockIdx.x & 4095;
  int lane = threadIdx.x;
  const float* xb = xyz + b * 3 * N_ALL;
  float qx = xb[s];
  float qy = xb[N_ALL + s];
  float qz = xb[2 * N_ALL + s];
  float qn = qx * qx + qy * qy + qz * qz;

  unsigned long long list = ~0ULL;    // lanes 0..31: sorted (keybits<<32|idx)
  unsigned long long worst = ~0ULL;   // broadcast copy of list[31]

  for (int n0 = 0; n0 < N_ALL; n0 += 256) {
    unsigned long long key[4];
#pragma unroll
    for (int t = 0; t < 4; t++) {
      int n = n0 + (t << 6) + lane;
      float x = xb[n];
      float y = xb[N_ALL + n];
      float z = xb[2 * N_ALL + n];
      float xn = x * x + y * y + z * z;
      float dt = qx * x + qy * y + qz * z;
      float d = (qn + xn) - 2.0f * dt;
      unsigned du = __float_as_uint(d);
      du ^= ((unsigned)(((int)du) >> 31)) | 0x80000000u;   // order-preserving
      key[t] = (((unsigned long long)du) << 32) | (unsigned)(n);
    }
    unsigned long long m = umin64(umin64(key[0], key[1]), umin64(key[2], key[3]));
    if (__ballot(m < worst)) {
#pragma unroll
      for (int t = 0; t < 4; t++) {
        unsigned long long cand = key[t];
        while (true) {
          unsigned long long ball = __ballot(cand < worst);
          if (!ball) break;
          int j = __builtin_ctzll(ball);
          unsigned long long bk = shfl64(cand, j);
          if (lane == j) cand = ~0ULL;                 // retire
          unsigned long long up = shflup64(list);
          unsigned long long lm = __ballot(bk < list) & 0xFFFFFFFFULL;
          int pos = __builtin_ctzll(lm);               // bit31 set (bk < list[31])
          if (lane == pos) list = bk;
          else if (lane > pos && lane < 32) list = up;
          worst = shfl64(list, 31);
        }
      }
    }
  }
  if (lane < 32)
    g_knn[(blockIdx.x << 5) | lane] = (unsigned short)(list & 0xFFFF);
}

// ---------------- pass A: gather + layer0 GEMM -> g_x0 ----------------
__global__ __launch_bounds__(256, 4) void k_l0(const float* __restrict__ xyz) {
  int p = blockIdx.x * 256 + threadIdx.x;
  int s = (p >> 5) & 4095;
  int b = p >> 17;
  int idx = g_knn[p];
  const float* xb = xyz + b * 3 * N_ALL;
  float feat[68];
  feat[0] = xb[idx] - xb[s];
  feat[1] = xb[N_ALL + idx] - xb[N_ALL + s];
  feat[2] = xb[2 * N_ALL + idx] - xb[2 * N_ALL + s];
  const float4* pr4 = (const float4*)(g_pt + ((size_t)(b * N_ALL + idx)) * 64);
#pragma unroll
  for (int i = 0; i < 16; i++) {
    float4 q = pr4[i];
    feat[3 + 4 * i + 0] = q.x;
    feat[3 + 4 * i + 1] = q.y;
    feat[3 + 4 * i + 2] = q.z;
    feat[3 + 4 * i + 3] = q.w;
  }
  feat[67] = 0.0f;
  for (int c = 0; c < 64; c++) {
    float acc = 0.f;
#pragma unroll
    for (int j = 0; j < 68; j++) acc = fmaf(g_W0f[c * 68 + j], feat[j], acc);
    g_x0[(size_t)c * P_TOT + p] = acc;
  }
}

// ---------------- streaming per-channel stats: part[c]=sum, part[nch+c]=sumsq ----------------
__global__ __launch_bounds__(256) void k_red(const float* __restrict__ x,
                                             float* __restrict__ part, int nch) {
  int c = blockIdx.x >> 3;
  int i = blockIdx.x & 7;
  const float4* src = (const float4*)(x + (size_t)c * P_TOT + ((size_t)i << 15));
  float s = 0.f, q = 0.f;
  for (int t = threadIdx.x; t < 8192; t += 256) {
    float4 v = src[t];
    s += v.x + v.y + v.z + v.w;
    q = fmaf(v.x, v.x, q); q = fmaf(v.y, v.y, q);
    q = fmaf(v.z, v.z, q); q = fmaf(v.w, v.w, q);
  }
#pragma unroll
  for (int off = 32; off; off >>= 1) { s += __shfl_xor(s, off, 64); q += __shfl_xor(q, off, 64); }
  __shared__ float ls[4], lq[4];
  int wid = threadIdx.x >> 6;
  if ((threadIdx.x & 63) == 0) { ls[wid] = s; lq[wid] = q; }
  __syncthreads();
  if (threadIdx.x == 0) {
    atomicAdd(part + c,       ls[0] + ls[1] + ls[2] + ls[3]);
    atomicAdd(part + nch + c, lq[0] + lq[1] + lq[2] + lq[3]);
  }
}

// ---------------- pass B: BN0+act on g_x0, layer1 GEMM -> g_x1 ----------------
__global__ __launch_bounds__(256, 4) void k_l1(const float* __restrict__ g0,
                                               const float* __restrict__ b0) {
  __shared__ float sc[64], sh[64];
  if (threadIdx.x < 64) {
    int c = threadIdx.x;
    float m = g_part0[c] / (float)P_TOT;
    float v = g_part0[64 + c] / (float)P_TOT - m * m;
    float scale = g0[c] / sqrtf(v + EPSV);
    sc[c] = scale; sh[c] = b0[c] - m * scale;
  }
  __syncthreads();
  int p = blockIdx.x * 256 + threadIdx.x;
  float act0[64];
#pragma unroll
  for (int c = 0; c < 64; c++) {
    float a = g_x0[(size_t)c * P_TOT + p] * sc[c] + sh[c];
    act0[c] = a >= 0.f ? a : LEAK * a;
  }
  for (int c = 0; c < 64; c++) {
    float acc = 0.f;
#pragma unroll
    for (int j = 0; j < 64; j++) acc = fmaf(g_W1f[c * 64 + j], act0[j], acc);
    g_x1[(size_t)c * P_TOT + p] = acc;
  }
}

// ---------------- pass C: BN1+act on g_x1, layer2 GEMM -> g_x2 ----------------
__global__ __launch_bounds__(256, 4) void k_l2(const float* __restrict__ g1,
                                               const float* __restrict__ b1) {
  __shared__ float sc[64], sh[64];
  if (threadIdx.x < 64) {
    int c = threadIdx.x;
    float m = g_part1[c] / (float)P_TOT;
    float v = g_part1[64 + c] / (float)P_TOT - m * m;
    float scale = g1[c] / sqrtf(v + EPSV);
    sc[c] = scale; sh[c] = b1[c] - m * scale;
  }
  __syncthreads();
  int p = blockIdx.x * 256 + threadIdx.x;
  float act1[64];
#pragma unroll
  for (int c = 0; c < 64; c++) {
    float a = g_x1[(size_t)c * P_TOT + p] * sc[c] + sh[c];
    act1[c] = a >= 0.f ? a : LEAK * a;
  }
  for (int c = 0; c < 128; c++) {
    float acc = 0.f;
#pragma unroll
    for (int j = 0; j < 64; j++) acc = fmaf(g_W2f[c * 64 + j], act1[j], acc);
    g_x2[(size_t)c * P_TOT + p] = acc;
  }
}

// ---------------- epilogue: BN2+act over k-extremum from g_x2, write f32 ----------------
__global__ __launch_bounds__(256) void k_epi(const float* __restrict__ g2,
                                             const float* __restrict__ b2,
                                             float* __restrict__ out) {
  __shared__ float sc[128], sh[128];
  if (threadIdx.x < 128) {
    int c = threadIdx.x;
    float m = g_part2[c] / (float)P_TOT;
    float v = g_part2[128 + c] / (float)P_TOT - m * m;
    float scale = g2[c] / sqrtf(v + EPSV);
    sc[c] = scale; sh[c] = b2[c] - m * scale;
  }
  __syncthreads();
  int i = blockIdx.x * 256 + threadIdx.x;   // < 1048576
  int s = i & 4095;
  int c = (i >> 12) & 127;
  int b = i >> 19;
  const float4* v4 = (const float4*)(g_x2 + (size_t)c * P_TOT + (((size_t)((b << 12) | s)) << 5));
  float mx = -3.4e38f, mn = 3.4e38f;
#pragma unroll
  for (int t = 0; t < 8; t++) {
    float4 v = v4[t];
    mx = fmaxf(mx, fmaxf(fmaxf(v.x, v.y), fmaxf(v.z, v.w)));
    mn = fminf(mn, fminf(fminf(v.x, v.y), fminf(v.z, v.w)));
  }
  float scale = sc[c];
  float t = (scale >= 0.f ? mx : mn) * scale + sh[c];
  t = t >= 0.f ? t : LEAK * t;
  out[24576 + i] = t;
}

extern "C" void kernel_launch(void* const* d_in, const int* in_sizes, int n_in,
                              void* d_out, int out_size, void* d_ws, size_t ws_size,
                              hipStream_t stream) {
  (void)in_sizes; (void)n_in; (void)out_size; (void)d_ws; (void)ws_size;
  const float* xyz    = (const float*)d_in[0];
  const float* points = (const float*)d_in[1];
  const float* W0     = (const float*)d_in[2];
  const float* W1     = (const float*)d_in[3];
  const float* W2     = (const float*)d_in[4];
  const float* g0     = (const float*)d_in[5];
  const float* b0     = (const float*)d_in[6];
  const float* g1     = (const float*)d_in[7];
  const float* b1     = (const float*)d_in[8];
  const float* g2     = (const float*)d_in[9];
  const float* b2     = (const float*)d_in[10];
  float* out = (float*)d_out;

  float *part0, *part1, *part2, *x0, *x1, *x2;
  hipGetSymbolAddress((void**)&part0, HIP_SYMBOL(g_part0));
  hipGetSymbolAddress((void**)&part1, HIP_SYMBOL(g_part1));
  hipGetSymbolAddress((void**)&part2, HIP_SYMBOL(g_part2));
  hipGetSymbolAddress((void**)&x0,    HIP_SYMBOL(g_x0));
  hipGetSymbolAddress((void**)&x1,    HIP_SYMBOL(g_x1));
  hipGetSymbolAddress((void**)&x2,    HIP_SYMBOL(g_x2));

  hipLaunchKernelGGL(k_newxyz, dim3(96),   dim3(256), 0, stream, xyz, out);
  hipLaunchKernelGGL(k_wprep,  dim3(1),    dim3(256), 0, stream, W0, W1, W2);
  hipLaunchKernelGGL(k_tpose,  dim3(512),  dim3(256), 0, stream, points);
  hipLaunchKernelGGL(k_knn,    dim3(8192), dim3(64),  0, stream, xyz);
  hipLaunchKernelGGL(k_l0,     dim3(1024), dim3(256), 0, stream, xyz);
  hipLaunchKernelGGL(k_red,    dim3(512),  dim3(256), 0, stream, x0, part0, 64);
  hipLaunchKernelGGL(k_l1,     dim3(1024), dim3(256), 0, stream, g0, b0);
  hipLaunchKernelGGL(k_red,    dim3(512),  dim3(256), 0, stream, x1, part1, 64);
  hipLaunchKernelGGL(k_l2,     dim3(1024), dim3(256), 0, stream, g1, b1);
  hipLaunchKernelGGL(k_red,    dim3(1024), dim3(256), 0, stream, x2, part2, 128);
  hipLaunchKernelGGL(k_epi,    dim3(4096), dim3(256), 0, stream, g2, b2, out);
}

// Round 9
// 404.398 us; speedup vs baseline: 4.2963x; 1.6650x over previous
//
#include <hip/hip_runtime.h>
#include <stdint.h>

#define N_ALL   16384
#define NPOINT  4096
#define KNN_K   32
#define BATCH   2
#define P_TOT   (BATCH*NPOINT*KNN_K)   /* 262144 */
#define P_TOTF  262144.0f
#define EPSV    1e-5f

typedef __attribute__((ext_vector_type(8))) short bf16x8;
typedef __attribute__((ext_vector_type(4))) float f32x4;

// ---- all scratch in module-static device memory; d_ws untouched ----
__device__ unsigned short g_knn[P_TOT];                                   // 512 KB
__device__ float g_xn[BATCH*N_ALL];                                       // 128 KB
__device__ __attribute__((aligned(16))) short g_ptb[BATCH*N_ALL*64];      // 4 MB  [b,n][64c] bf16
__device__ __attribute__((aligned(16))) short g_x0b[(size_t)P_TOT*64];    // 32 MB [p][64] bf16
__device__ __attribute__((aligned(16))) short g_x1b[(size_t)P_TOT*64];    // 32 MB
__device__ __attribute__((aligned(16))) short g_x2b[(size_t)P_TOT*128];   // 64 MB
__device__ __attribute__((aligned(16))) short g_Wb0[4*3*64*8];            // swizzled A-frags
__device__ __attribute__((aligned(16))) short g_Wb1[4*2*64*8];
__device__ __attribute__((aligned(16))) short g_Wb2[8*2*64*8];
__device__ float g_part0[128], g_part1[128], g_part2[256];

__device__ __forceinline__ float b2f(short s) {
  union { unsigned u; float f; } v; v.u = ((unsigned)(unsigned short)s) << 16; return v.f;
}
__device__ __forceinline__ short f2b(float f) {
  union { float f; unsigned u; } v; v.f = f;
  unsigned u = v.u;
  u += 0x7FFFu + ((u >> 16) & 1u);
  return (short)(u >> 16);
}
__device__ __forceinline__ unsigned long long shfl64(unsigned long long v, int src) {
  int lo = __shfl((int)(unsigned)(v & 0xFFFFFFFFULL), src, 64);
  int hi = __shfl((int)(unsigned)(v >> 32), src, 64);
  return (((unsigned long long)(unsigned)hi) << 32) | (unsigned)lo;
}
__device__ __forceinline__ unsigned long long shflup64(unsigned long long v) {
  int lo = __shfl_up((int)(unsigned)(v & 0xFFFFFFFFULL), 1, 64);
  int hi = __shfl_up((int)(unsigned)(v >> 32), 1, 64);
  return (((unsigned long long)(unsigned)hi) << 32) | (unsigned)lo;
}
__device__ __forceinline__ unsigned long long umin64(unsigned long long a, unsigned long long b) {
  return a < b ? a : b;
}

// ---------------- new_xyz passthrough copy ----------------
__global__ void k_newxyz(const float* __restrict__ xyz, float* __restrict__ out) {
  int i = blockIdx.x * 256 + threadIdx.x;   // < 24576
  int s = i & 4095;
  int c = (i >> 12) % 3;
  int b = i / 12288;
  out[i] = xyz[(b * 3 + c) * N_ALL + s];
}

// ---------------- prep: swizzle weights to per-lane MFMA A-frags, zero parts ----------------
// A-frag element: m = 16*mt + (lane&15), k = 32*kt + (lane>>4)*8 + j
// feat order layer0: k 0..63 = grouped (W0 col 3+k), 64..66 = direction (W0 col k-64), 67+ = 0
__global__ void k_prep(const float* __restrict__ W0, const float* __restrict__ W1,
                       const float* __restrict__ W2) {
  int t = threadIdx.x;
  for (int i = t; i < 4 * 3 * 64 * 8; i += 256) {
    int j = i & 7, lane = (i >> 3) & 63, rest = i >> 9;
    int kt = rest % 3, mt = rest / 3;
    int m = 16 * mt + (lane & 15);
    int k = 32 * kt + (lane >> 4) * 8 + j;
    float v = 0.f;
    if (k < 64) v = W0[m * 67 + 3 + k];
    else if (k < 67) v = W0[m * 67 + (k - 64)];
    g_Wb0[i] = f2b(v);
  }
  for (int i = t; i < 4 * 2 * 64 * 8; i += 256) {
    int j = i & 7, lane = (i >> 3) & 63;
    int kt = (i >> 9) & 1, mt = i >> 10;
    int m = 16 * mt + (lane & 15);
    int k = 32 * kt + (lane >> 4) * 8 + j;
    g_Wb1[i] = f2b(W1[m * 64 + k]);
  }
  for (int i = t; i < 8 * 2 * 64 * 8; i += 256) {
    int j = i & 7, lane = (i >> 3) & 63;
    int kt = (i >> 9) & 1, mt = i >> 10;
    int m = 16 * mt + (lane & 15);
    int k = 32 * kt + (lane >> 4) * 8 + j;
    g_Wb2[i] = f2b(W2[m * 64 + k]);
  }
  if (t < 128) { g_part0[t] = 0.f; g_part1[t] = 0.f; }
  g_part2[t] = 0.f;
}

// ---------------- transpose points [b][c][n] -> g_ptb [b,n][c] bf16 ----------------
__global__ __launch_bounds__(256) void k_tpose(const float* __restrict__ points) {
  __shared__ float tile[64][65];
  int b  = blockIdx.x >> 8;
  int n0 = (blockIdx.x & 255) << 6;
#pragma unroll
  for (int r = 0; r < 16; r++) {
    int lin = r * 256 + threadIdx.x;
    int c = lin >> 6, nn = lin & 63;
    tile[c][nn] = points[((size_t)(b * 64 + c)) * N_ALL + n0 + nn];
  }
  __syncthreads();
#pragma unroll
  for (int r = 0; r < 16; r++) {
    int lin = r * 256 + threadIdx.x;
    int nn = lin >> 6, c = lin & 63;
    g_ptb[((size_t)(b * N_ALL + n0 + nn)) * 64 + c] = f2b(tile[c][nn]);
  }
}

// ---------------- per-point squared norms (exact reference op order) ----------------
__global__ void k_xn(const float* __restrict__ xyz) {
#pragma clang fp contract(off)
  int i = blockIdx.x * 256 + threadIdx.x;   // < 32768
  int b = i >> 14, n = i & 16383;
  const float* xb = xyz + b * 3 * N_ALL;
  float x = xb[n], y = xb[N_ALL + n], z = xb[2 * N_ALL + n];
  g_xn[i] = x * x + y * y + z * z;
}

// ---------------- KNN: 4 queries/block, one wave each; exact f32 distances ----------------
__global__ __launch_bounds__(256) void k_knn(const float* __restrict__ xyz) {
#pragma clang fp contract(off)
  int q = blockIdx.x * 4 + (threadIdx.x >> 6);   // 0..8191
  int b = q >> 12, s = q & 4095;
  int lane = threadIdx.x & 63;
  const float* xb = xyz + b * 3 * N_ALL;
  const float* xnb = g_xn + (b << 14);
  float qx = xb[s], qy = xb[N_ALL + s], qz = xb[2 * N_ALL + s];
  float qn = xnb[s];

  unsigned long long list = ~0ULL;    // lanes 0..31: sorted (keybits<<32|idx)
  unsigned long long worst = ~0ULL;   // broadcast copy of list[31]

  for (int n0 = 0; n0 < N_ALL; n0 += 256) {
    unsigned long long key[4];
#pragma unroll
    for (int t = 0; t < 4; t++) {
      int n = n0 + (t << 6) + lane;
      float x = xb[n];
      float y = xb[N_ALL + n];
      float z = xb[2 * N_ALL + n];
      float dt = qx * x + qy * y + qz * z;
      float d = (qn + xnb[n]) - 2.0f * dt;
      unsigned du = __float_as_uint(d);
      du ^= ((unsigned)(((int)du) >> 31)) | 0x80000000u;   // order-preserving
      key[t] = (((unsigned long long)du) << 32) | (unsigned)(n);
    }
    unsigned long long m = umin64(umin64(key[0], key[1]), umin64(key[2], key[3]));
    if (__ballot(m < worst)) {
#pragma unroll
      for (int t = 0; t < 4; t++) {
        unsigned long long cand = key[t];
        while (true) {
          unsigned long long ball = __ballot(cand < worst);
          if (!ball) break;
          int j = __builtin_ctzll(ball);
          unsigned long long bk = shfl64(cand, j);
          if (lane == j) cand = ~0ULL;                 // retire
          unsigned long long up = shflup64(list);
          unsigned long long lm = __ballot(bk < list) & 0xFFFFFFFFULL;
          int pos = __builtin_ctzll(lm);
          if (lane == pos) list = bk;
          else if (lane > pos && lane < 32) list = up;
          worst = shfl64(list, 31);
        }
      }
    }
  }
  if (lane < 32)
    g_knn[(q << 5) | lane] = (unsigned short)(list & 0xFFFF);
}

// ---------------- layer0: gather feats to LDS, MFMA K=96 -> x0 bf16 ----------------
__global__ __launch_bounds__(256) void k_l0(const float* __restrict__ xyz) {
  __shared__ short feats[256][104];   // row 208B: 16B-aligned
  int t = threadIdx.x;
  int p0 = blockIdx.x * 256;
  {
    int p = p0 + t;
    int idx = g_knn[p];
    int s = (p >> 5) & 4095;
    int b = p >> 17;
    const short* src = g_ptb + ((size_t)((b << 14) + idx) << 6);
#pragma unroll
    for (int i = 0; i < 8; i++)          // 8 x int4 = 128 B = all 64 bf16 (R8 bug: was 4)
      ((int4*)&feats[t][0])[i] = ((const int4*)src)[i];
    const float* xb = xyz + b * 3 * N_ALL;
    feats[t][64] = f2b(xb[idx] - xb[s]);
    feats[t][65] = f2b(xb[N_ALL + idx] - xb[N_ALL + s]);
    feats[t][66] = f2b(xb[2 * N_ALL + idx] - xb[2 * N_ALL + s]);
#pragma unroll
    for (int c = 67; c < 96; c++) feats[t][c] = 0;
  }
  __syncthreads();
  int lane = t & 63, wv = t >> 6;
  int l15 = lane & 15, quad = lane >> 4;
  bf16x8 A[4][3];
#pragma unroll
  for (int mt = 0; mt < 4; mt++)
#pragma unroll
    for (int kt = 0; kt < 3; kt++)
      A[mt][kt] = *(const bf16x8*)(g_Wb0 + (((mt * 3 + kt) * 64 + lane) << 3));
  f32x4 C[4][4];
#pragma unroll
  for (int mt = 0; mt < 4; mt++)
#pragma unroll
    for (int nt = 0; nt < 4; nt++) C[mt][nt] = 0.f;
#pragma unroll
  for (int kt = 0; kt < 3; kt++)
#pragma unroll
    for (int nt = 0; nt < 4; nt++) {
      bf16x8 B = *(const bf16x8*)(&feats[wv * 64 + nt * 16 + l15][kt * 32 + quad * 8]);
#pragma unroll
      for (int mt = 0; mt < 4; mt++)
        C[mt][nt] = __builtin_amdgcn_mfma_f32_16x16x32_bf16(A[mt][kt], B, C[mt][nt], 0, 0, 0);
    }
#pragma unroll
  for (int mt = 0; mt < 4; mt++)
#pragma unroll
    for (int nt = 0; nt < 4; nt++) {
      int p = p0 + wv * 64 + nt * 16 + l15;
      int c0 = mt * 16 + quad * 4;
      short4 o;
      o.x = f2b(C[mt][nt][0]); o.y = f2b(C[mt][nt][1]);
      o.z = f2b(C[mt][nt][2]); o.w = f2b(C[mt][nt][3]);
      *(short4*)(g_x0b + ((size_t)p << 6) + c0) = o;
    }
}

// ---------------- layer1: BN0+leaky on x0 frags, MFMA K=64 -> x1 bf16 ----------------
__global__ __launch_bounds__(256) void k_l1(const float* __restrict__ g0,
                                            const float* __restrict__ b0) {
  __shared__ float scA[64], shA[64];
  int t = threadIdx.x;
  if (t < 64) {
    float m = g_part0[t] / P_TOTF;
    float v = g_part0[64 + t] / P_TOTF - m * m;
    float sc = g0[t] / sqrtf(v + EPSV);
    scA[t] = sc; shA[t] = b0[t] - m * sc;
  }
  __syncthreads();
  int lane = t & 63, wv = t >> 6;
  int l15 = lane & 15, quad = lane >> 4;
  int p0 = blockIdx.x * 256 + wv * 64;
  float scv[2][8], shv[2][8];
#pragma unroll
  for (int kt = 0; kt < 2; kt++)
#pragma unroll
    for (int j = 0; j < 8; j++) {
      int c = kt * 32 + quad * 8 + j;
      scv[kt][j] = scA[c]; shv[kt][j] = shA[c];
    }
  bf16x8 A[4][2];
#pragma unroll
  for (int mt = 0; mt < 4; mt++)
#pragma unroll
    for (int kt = 0; kt < 2; kt++)
      A[mt][kt] = *(const bf16x8*)(g_Wb1 + (((mt * 2 + kt) * 64 + lane) << 3));
  f32x4 C[4][4];
#pragma unroll
  for (int mt = 0; mt < 4; mt++)
#pragma unroll
    for (int nt = 0; nt < 4; nt++) C[mt][nt] = 0.f;
#pragma unroll
  for (int kt = 0; kt < 2; kt++)
#pragma unroll
    for (int nt = 0; nt < 4; nt++) {
      const short* src = g_x0b + (((size_t)(p0 + nt * 16 + l15)) << 6) + kt * 32 + quad * 8;
      bf16x8 raw = *(const bf16x8*)src;
      bf16x8 B;
#pragma unroll
      for (int j = 0; j < 8; j++) {
        float a = b2f(raw[j]) * scv[kt][j] + shv[kt][j];
        a = fmaxf(a, 0.1f * a);
        B[j] = f2b(a);
      }
#pragma unroll
      for (int mt = 0; mt < 4; mt++)
        C[mt][nt] = __builtin_amdgcn_mfma_f32_16x16x32_bf16(A[mt][kt], B, C[mt][nt], 0, 0, 0);
    }
#pragma unroll
  for (int mt = 0; mt < 4; mt++)
#pragma unroll
    for (int nt = 0; nt < 4; nt++) {
      int p = p0 + nt * 16 + l15;
      int c0 = mt * 16 + quad * 4;
      short4 o;
      o.x = f2b(C[mt][nt][0]); o.y = f2b(C[mt][nt][1]);
      o.z = f2b(C[mt][nt][2]); o.w = f2b(C[mt][nt][3]);
      *(short4*)(g_x1b + ((size_t)p << 6) + c0) = o;
    }
}

// ---------------- layer2: BN1+leaky on x1 frags, MFMA K=64, M=128 -> x2 bf16 ----------------
__global__ __launch_bounds__(256) void k_l2(const float* __restrict__ g1,
                                            const float* __restrict__ b1) {
  __shared__ float scA[64], shA[64];
  int t = threadIdx.x;
  if (t < 64) {
    float m = g_part1[t] / P_TOTF;
    float v = g_part1[64 + t] / P_TOTF - m * m;
    float sc = g1[t] / sqrtf(v + EPSV);
    scA[t] = sc; shA[t] = b1[t] - m * sc;
  }
  __syncthreads();
  int lane = t & 63, wv = t >> 6;
  int l15 = lane & 15, quad = lane >> 4;
  int chh = wv & 1;                      // channel half: mt_g = 4*chh + mt
  int p0 = blockIdx.x * 128 + (wv >> 1) * 64;
  float scv[2][8], shv[2][8];
#pragma unroll
  for (int kt = 0; kt < 2; kt++)
#pragma unroll
    for (int j = 0; j < 8; j++) {
      int c = kt * 32 + quad * 8 + j;
      scv[kt][j] = scA[c]; shv[kt][j] = shA[c];
    }
  bf16x8 A[4][2];
#pragma unroll
  for (int mt = 0; mt < 4; mt++)
#pragma unroll
    for (int kt = 0; kt < 2; kt++)
      A[mt][kt] = *(const bf16x8*)(g_Wb2 + ((((4 * chh + mt) * 2 + kt) * 64 + lane) << 3));
  f32x4 C[4][4];
#pragma unroll
  for (int mt = 0; mt < 4; mt++)
#pragma unroll
    for (int nt = 0; nt < 4; nt++) C[mt][nt] = 0.f;
#pragma unroll
  for (int kt = 0; kt < 2; kt++)
#pragma unroll
    for (int nt = 0; nt < 4; nt++) {
      const short* src = g_x1b + (((size_t)(p0 + nt * 16 + l15)) << 6) + kt * 32 + quad * 8;
      bf16x8 raw = *(const bf16x8*)src;
      bf16x8 B;
#pragma unroll
      for (int j = 0; j < 8; j++) {
        float a = b2f(raw[j]) * scv[kt][j] + shv[kt][j];
        a = fmaxf(a, 0.1f * a);
        B[j] = f2b(a);
      }
#pragma unroll
      for (int mt = 0; mt < 4; mt++)
        C[mt][nt] = __builtin_amdgcn_mfma_f32_16x16x32_bf16(A[mt][kt], B, C[mt][nt], 0, 0, 0);
    }
#pragma unroll
  for (int mt = 0; mt < 4; mt++)
#pragma unroll
    for (int nt = 0; nt < 4; nt++) {
      int p = p0 + nt * 16 + l15;
      int c0 = (4 * chh + mt) * 16 + quad * 4;
      short4 o;
      o.x = f2b(C[mt][nt][0]); o.y = f2b(C[mt][nt][1]);
      o.z = f2b(C[mt][nt][2]); o.w = f2b(C[mt][nt][3]);
      *(short4*)(g_x2b + ((size_t)p << 7) + c0) = o;
    }
}

// ---------------- streaming stats over bf16 [p][64] ----------------
__global__ __launch_bounds__(256) void k_red64(const short* __restrict__ x,
                                               float* __restrict__ part) {
  int t = threadIdx.x;
  int cl = t & 31, pr = t >> 5;
  float s0 = 0.f, s1 = 0.f, q0 = 0.f, q1 = 0.f;
  int pbase = blockIdx.x * 1024;
  for (int i = 0; i < 128; i++) {
    int p = pbase + pr + i * 8;
    unsigned d = *(const unsigned*)(x + ((size_t)p << 6) + cl * 2);
    float a = b2f((short)(d & 0xFFFF));
    float b = b2f((short)(d >> 16));
    s0 += a; q0 = fmaf(a, a, q0);
    s1 += b; q1 = fmaf(b, b, q1);
  }
  __shared__ float sm[8][64], sq[8][64];
  sm[pr][cl * 2] = s0; sm[pr][cl * 2 + 1] = s1;
  sq[pr][cl * 2] = q0; sq[pr][cl * 2 + 1] = q1;
  __syncthreads();
  if (t < 64) {
    float S = 0.f, Q = 0.f;
#pragma unroll
    for (int r = 0; r < 8; r++) { S += sm[r][t]; Q += sq[r][t]; }
    atomicAdd(part + t, S); atomicAdd(part + 64 + t, Q);
  }
}

// ---------------- streaming stats over bf16 [p][128] ----------------
__global__ __launch_bounds__(256) void k_red128(const short* __restrict__ x,
                                                float* __restrict__ part) {
  int t = threadIdx.x;
  int cl = t & 63, pr = t >> 6;
  float s0 = 0.f, s1 = 0.f, q0 = 0.f, q1 = 0.f;
  int pbase = blockIdx.x * 1024;
  for (int i = 0; i < 256; i++) {
    int p = pbase + pr + i * 4;
    unsigned d = *(const unsigned*)(x + ((size_t)p << 7) + cl * 2);
    float a = b2f((short)(d & 0xFFFF));
    float b = b2f((short)(d >> 16));
    s0 += a; q0 = fmaf(a, a, q0);
    s1 += b; q1 = fmaf(b, b, q1);
  }
  __shared__ float sm[4][128], sq[4][128];
  sm[pr][cl * 2] = s0; sm[pr][cl * 2 + 1] = s1;
  sq[pr][cl * 2] = q0; sq[pr][cl * 2 + 1] = q1;
  __syncthreads();
  if (t < 128) {
    float S = 0.f, Q = 0.f;
#pragma unroll
    for (int r = 0; r < 4; r++) { S += sm[r][t]; Q += sq[r][t]; }
    atomicAdd(part + t, S); atomicAdd(part + 128 + t, Q);
  }
}

// ---------------- epilogue: max/min over k from x2, BN2+leaky, write f32 ----------------
__global__ __launch_bounds__(256) void k_epi(const float* __restrict__ g2,
                                             const float* __restrict__ b2,
                                             float* __restrict__ out) {
  __shared__ float scA[128], shA[128];
  int t = threadIdx.x;
  if (t < 128) {
    float m = g_part2[t] / P_TOTF;
    float v = g_part2[128 + t] / P_TOTF - m * m;
    float sc = g2[t] / sqrtf(v + EPSV);
    scA[t] = sc; shA[t] = b2[t] - m * sc;
  }
  __syncthreads();
  int c = t & 127, sl = t >> 7;
  int sg = blockIdx.x * 2 + sl;                  // 0..8191
  size_t base = (((size_t)sg) << 12) + c;        // (sg*32)*128 + c
  float mx = -3.4e38f, mn = 3.4e38f;
#pragma unroll
  for (int k = 0; k < 32; k++) {
    float v = b2f(g_x2b[base + (size_t)k * 128]);
    mx = fmaxf(mx, v); mn = fminf(mn, v);
  }
  float sc = scA[c];
  float a = (sc >= 0.f ? mx : mn) * sc + shA[c];
  a = fmaxf(a, 0.1f * a);
  int b = sg >> 12, s = sg & 4095;
  out[24576 + (((b * 128 + c) << 12) | s)] = a;
}

extern "C" void kernel_launch(void* const* d_in, const int* in_sizes, int n_in,
                              void* d_out, int out_size, void* d_ws, size_t ws_size,
                              hipStream_t stream) {
  (void)in_sizes; (void)n_in; (void)out_size; (void)d_ws; (void)ws_size;
  const float* xyz    = (const float*)d_in[0];
  const float* points = (const float*)d_in[1];
  const float* W0     = (const float*)d_in[2];
  const float* W1     = (const float*)d_in[3];
  const float* W2     = (const float*)d_in[4];
  const float* g0     = (const float*)d_in[5];
  const float* b0     = (const float*)d_in[6];
  const float* g1     = (const float*)d_in[7];
  const float* b1     = (const float*)d_in[8];
  const float* g2     = (const float*)d_in[9];
  const float* b2     = (const float*)d_in[10];
  float* out = (float*)d_out;

  short *x0b, *x1b, *x2b; float *part0, *part1, *part2;
  hipGetSymbolAddress((void**)&x0b,   HIP_SYMBOL(g_x0b));
  hipGetSymbolAddress((void**)&x1b,   HIP_SYMBOL(g_x1b));
  hipGetSymbolAddress((void**)&x2b,   HIP_SYMBOL(g_x2b));
  hipGetSymbolAddress((void**)&part0, HIP_SYMBOL(g_part0));
  hipGetSymbolAddress((void**)&part1, HIP_SYMBOL(g_part1));
  hipGetSymbolAddress((void**)&part2, HIP_SYMBOL(g_part2));

  hipLaunchKernelGGL(k_newxyz, dim3(96),   dim3(256), 0, stream, xyz, out);
  hipLaunchKernelGGL(k_prep,   dim3(1),    dim3(256), 0, stream, W0, W1, W2);
  hipLaunchKernelGGL(k_tpose,  dim3(512),  dim3(256), 0, stream, points);
  hipLaunchKernelGGL(k_xn,     dim3(128),  dim3(256), 0, stream, xyz);
  hipLaunchKernelGGL(k_knn,    dim3(2048), dim3(256), 0, stream, xyz);
  hipLaunchKernelGGL(k_l0,     dim3(1024), dim3(256), 0, stream, xyz);
  hipLaunchKernelGGL(k_red64,  dim3(256),  dim3(256), 0, stream, x0b, part0);
  hipLaunchKernelGGL(k_l1,     dim3(1024), dim3(256), 0, stream, g0, b0);
  hipLaunchKernelGGL(k_red64,  dim3(256),  dim3(256), 0, stream, x1b, part1);
  hipLaunchKernelGGL(k_l2,     dim3(2048), dim3(256), 0, stream, g1, b1);
  hipLaunchKernelGGL(k_red128, dim3(256),  dim3(256), 0, stream, x2b, part2);
  hipLaunchKernelGGL(k_epi,    dim3(4096), dim3(256), 0, stream, g2, b2, out);
}